// Round 1
// 699.769 us; speedup vs baseline: 1.0312x; 1.0312x over previous
//
#include <hip/hip_runtime.h>
#include <hip/hip_bf16.h>

// Problem constants
// inputs [512][4][124][124], conv1 w[32][4][8][8] s4 -> [512][32][30][30] (bf16, MFMA)
// conv2 w[64][32][4][4] s2 -> [512][64][14][14]   (MFMA implicit GEMM)
// conv3 w[32][64][3][3] s1 -> [512][32][12][12] bf16 -> flat 4608
// fc [512,4608] -> xs [512][512] relu  (MFMA)
// gi = xs @ w_ih^T + b_ih : [512][1536]
// GRU T=32, N=16, H=512 ; heads A=6
// d_out: value[512] | alp[512] | ent[512] | states_out[16*512]

typedef __bf16 bf16x8_t __attribute__((ext_vector_type(8)));
typedef float  f32x4_t  __attribute__((ext_vector_type(4)));

__device__ __forceinline__ unsigned int pack_bf2(float a, float b) {
  union { __bf16 h[2]; unsigned int u; } c;
  c.h[0] = (__bf16)a; c.h[1] = (__bf16)b;
  return c.u;
}
__device__ __forceinline__ unsigned short f2bf(float x) {
  union { __bf16 h; unsigned short s; } c; c.h = (__bf16)x; return c.s;
}

// ---------------- conv1: bf16 MFMA implicit GEMM ----------------
// M = 512*900 px, N = 32 oc, K = 4c*8ky*8kx = 256. 7200 blocks x 256 thr.
__global__ __launch_bounds__(256) void conv1_mfma(const float* __restrict__ x,
        const float* __restrict__ w, const float* __restrict__ bias,
        unsigned short* __restrict__ out) {
  __shared__ __align__(16) unsigned short pt[64*264];   // 33.8 KB, K=256 pad->264
  const int tid  = threadIdx.x;
  const int lane = tid & 63;
  const int wv   = tid >> 6;
  const int px0  = blockIdx.x * 64;
  {
    int px = px0 + lane;
    int n = px / 900, q = px % 900;
    int oy = q / 30, ox = q % 30;
    const float* base = x + ((size_t)(n*4 + wv)*124 + oy*4)*124 + ox*4;
    #pragma unroll
    for (int ky = 0; ky < 8; ++ky) {
      const float* src = base + ky*124;
      float4 f0 = *(const float4*)src;
      float4 f1 = *(const float4*)(src + 4);
      uint4 v;
      v.x = pack_bf2(f0.x, f0.y); v.y = pack_bf2(f0.z, f0.w);
      v.z = pack_bf2(f1.x, f1.y); v.w = pack_bf2(f1.z, f1.w);
      *(uint4*)&pt[lane*264 + wv*64 + ky*8] = v;
    }
  }
  bf16x8_t wfr[2][8];
  {
    int m = lane & 15, q = lane >> 4;
    #pragma unroll
    for (int tt = 0; tt < 2; ++tt) {
      const float* wrow = w + (size_t)(tt*16 + m)*256 + q*8;
      #pragma unroll
      for (int ks = 0; ks < 8; ++ks) {
        float4 f0 = *(const float4*)(wrow + ks*32);
        float4 f1 = *(const float4*)(wrow + ks*32 + 4);
        bf16x8_t v;
        v[0]=(__bf16)f0.x; v[1]=(__bf16)f0.y; v[2]=(__bf16)f0.z; v[3]=(__bf16)f0.w;
        v[4]=(__bf16)f1.x; v[5]=(__bf16)f1.y; v[6]=(__bf16)f1.z; v[7]=(__bf16)f1.w;
        wfr[tt][ks] = v;
      }
    }
  }
  __syncthreads();
  f32x4_t acc0 = {0.f,0.f,0.f,0.f}, acc1 = {0.f,0.f,0.f,0.f};
  {
    const unsigned short* prow = &pt[(wv*16 + (lane & 15))*264 + (lane >> 4)*8];
    #pragma unroll
    for (int ks = 0; ks < 8; ++ks) {
      union { bf16x8_t v; uint4 u; } fb;
      fb.u = *(const uint4*)(prow + ks*32);
      acc0 = __builtin_amdgcn_mfma_f32_16x16x32_bf16(wfr[0][ks], fb.v, acc0, 0, 0, 0);
      acc1 = __builtin_amdgcn_mfma_f32_16x16x32_bf16(wfr[1][ks], fb.v, acc1, 0, 0, 0);
    }
  }
  {
    int q4 = lane >> 4;
    int px = px0 + wv*16 + (lane & 15);
    int n = px / 900, q = px % 900;
    const float sc = 1.0f / 255.0f;
    #pragma unroll
    for (int rg = 0; rg < 4; ++rg) {
      int oc0 = q4*4 + rg;
      out[((size_t)n*32 + oc0)*900 + q]      = f2bf(fmaxf(acc0[rg]*sc + bias[oc0], 0.f));
      out[((size_t)n*32 + oc0 + 16)*900 + q] = f2bf(fmaxf(acc1[rg]*sc + bias[oc0 + 16], 0.f));
    }
  }
}

// ---------------- conv2: bf16 MFMA implicit GEMM (verified r9) ----------------
__global__ __launch_bounds__(256) void conv2_mfma(const unsigned short* __restrict__ in,
        const float* __restrict__ w, const float* __restrict__ bias,
        float* __restrict__ out) {
  __shared__ __align__(16) unsigned short pt[64*520];   // 65 KB
  const int tid  = threadIdx.x;
  const int lane = tid & 63;
  const int wv   = tid >> 6;
  const int px0  = blockIdx.x * 64;
  {
    int px = px0 + lane;
    int n = px / 196, q = px % 196;
    int oy = q / 14, ox = q % 14;
    const unsigned short* base = in + ((size_t)(n*32)*30 + oy*2)*30 + ox*2;
    #pragma unroll 4
    for (int it = 0; it < 32; ++it) {
      int c  = wv*8 + (it >> 2);
      int ky = it & 3;
      const unsigned short* src = base + (c*30 + ky)*30;
      unsigned int a0 = *(const unsigned int*)(src);
      unsigned int a1 = *(const unsigned int*)(src + 2);
      *(uint2*)&pt[lane*520 + c*16 + ky*4] = make_uint2(a0, a1);
    }
  }
  bf16x8_t wfr[16];
  {
    int m = lane & 15, q = lane >> 4;
    const float* wrow = w + (size_t)(wv*16 + m)*512 + q*8;
    #pragma unroll
    for (int ks = 0; ks < 16; ++ks) {
      float4 f0 = *(const float4*)(wrow + ks*32);
      float4 f1 = *(const float4*)(wrow + ks*32 + 4);
      bf16x8_t v;
      v[0] = (__bf16)f0.x; v[1] = (__bf16)f0.y; v[2] = (__bf16)f0.z; v[3] = (__bf16)f0.w;
      v[4] = (__bf16)f1.x; v[5] = (__bf16)f1.y; v[6] = (__bf16)f1.z; v[7] = (__bf16)f1.w;
      wfr[ks] = v;
    }
  }
  __syncthreads();
  f32x4_t acc[4];
  #pragma unroll
  for (int pxt = 0; pxt < 4; ++pxt) {
    f32x4_t a = {0.f, 0.f, 0.f, 0.f};
    const unsigned short* prow = &pt[(pxt*16 + (lane & 15))*520 + (lane >> 4)*8];
    #pragma unroll
    for (int ks = 0; ks < 16; ++ks) {
      union { bf16x8_t v; uint4 u; } fb;
      fb.u = *(const uint4*)(prow + ks*32);
      a = __builtin_amdgcn_mfma_f32_16x16x32_bf16(wfr[ks], fb.v, a, 0, 0, 0);
    }
    acc[pxt] = a;
  }
  {
    int q4 = lane >> 4;
    float b4[4];
    #pragma unroll
    for (int rg = 0; rg < 4; ++rg) b4[rg] = bias[wv*16 + q4*4 + rg];
    #pragma unroll
    for (int pxt = 0; pxt < 4; ++pxt) {
      int px = px0 + pxt*16 + (lane & 15);
      int n = px / 196, q = px % 196;
      #pragma unroll
      for (int rg = 0; rg < 4; ++rg) {
        int oc = wv*16 + q4*4 + rg;
        out[((size_t)n*64 + oc)*196 + q] = fmaxf(acc[pxt][rg] + b4[rg], 0.f);
      }
    }
  }
}

// ---------------- conv3 (fp32 compute, bf16 output for fc MFMA) ----------------
__global__ __launch_bounds__(256) void conv3_k(const float* __restrict__ in,
        const float* __restrict__ w, const float* __restrict__ bias,
        unsigned short* __restrict__ out) {
  __shared__ float wsT[9216];               // [(c*3+ky)*3+kx][oc]
  int och0 = blockIdx.y * 16;
  for (int i = threadIdx.x; i < 9216; i += 256) {
    int oc = i & 15, rest = i >> 4;
    int kx = rest % 3, t2 = rest / 3;
    int ky = t2 % 3, c = t2 / 3;
    wsT[i] = w[(size_t)(och0 + oc)*576 + c*9 + ky*3 + kx];
  }
  __syncthreads();
  int pidx = blockIdx.x * 256 + threadIdx.x;   // [0, 512*72)
  int n = pidx / 72;
  int q = pidx % 72;
  int oy0 = q / 12, ox0 = q % 12;
  int q1 = q + 72;
  int oy1 = q1 / 12, ox1 = q1 % 12;
  float acc0[16], acc1[16];
  #pragma unroll
  for (int oc = 0; oc < 16; ++oc) { float bb = bias[och0 + oc]; acc0[oc] = bb; acc1[oc] = bb; }
  for (int c = 0; c < 64; ++c) {
    #pragma unroll
    for (int ky = 0; ky < 3; ++ky) {
      const float* r0 = in + ((n*64 + c)*14 + oy0 + ky)*14 + ox0;
      const float* r1 = in + ((n*64 + c)*14 + oy1 + ky)*14 + ox1;
      float v0[3] = {r0[0], r0[1], r0[2]};
      float v1[3] = {r1[0], r1[1], r1[2]};
      #pragma unroll
      for (int kx = 0; kx < 3; ++kx) {
        const float4* wp = (const float4*)&wsT[((c*3 + ky)*3 + kx)*16];
        float4 wA = wp[0], wB = wp[1], wC = wp[2], wD = wp[3];
        float a = v0[kx], b = v1[kx];
        acc0[0] += a*wA.x; acc0[1] += a*wA.y; acc0[2]  += a*wA.z; acc0[3]  += a*wA.w;
        acc0[4] += a*wB.x; acc0[5] += a*wB.y; acc0[6]  += a*wB.z; acc0[7]  += a*wB.w;
        acc0[8] += a*wC.x; acc0[9] += a*wC.y; acc0[10] += a*wC.z; acc0[11] += a*wC.w;
        acc0[12]+= a*wD.x; acc0[13]+= a*wD.y; acc0[14] += a*wD.z; acc0[15] += a*wD.w;
        acc1[0] += b*wA.x; acc1[1] += b*wA.y; acc1[2]  += b*wA.z; acc1[3]  += b*wA.w;
        acc1[4] += b*wB.x; acc1[5] += b*wB.y; acc1[6]  += b*wB.z; acc1[7]  += b*wB.w;
        acc1[8] += b*wC.x; acc1[9] += b*wC.y; acc1[10] += b*wC.z; acc1[11] += b*wC.w;
        acc1[12]+= b*wD.x; acc1[13]+= b*wD.y; acc1[14] += b*wD.z; acc1[15] += b*wD.w;
      }
    }
  }
  #pragma unroll
  for (int oc = 0; oc < 16; ++oc) {
    out[(n*32 + och0 + oc)*144 + q]      = f2bf(fmaxf(acc0[oc], 0.f));
    out[(n*32 + och0 + oc)*144 + q + 72] = f2bf(fmaxf(acc1[oc], 0.f));
  }
}

// ---------------- fc: bf16 MFMA GEMM ----------------
__global__ __launch_bounds__(256) void fc_mfma(const unsigned short* __restrict__ A,
        const float* __restrict__ W, const float* __restrict__ bias,
        float* __restrict__ C) {
  __shared__ __align__(16) unsigned short As[64*72];
  __shared__ __align__(16) unsigned short Wsm[64*72];
  const int tid  = threadIdx.x;
  const int lane = tid & 63;
  const int wv   = tid >> 6;
  const int m0 = blockIdx.y * 64, n0 = blockIdx.x * 64;
  const int r  = tid >> 2;
  const int cq = (tid & 3) * 16;
  f32x4_t acc[4] = {{0,0,0,0},{0,0,0,0},{0,0,0,0},{0,0,0,0}};
  for (int k0 = 0; k0 < 4608; k0 += 64) {
    __syncthreads();
    {
      const uint4* src = (const uint4*)(A + (size_t)(m0 + r)*4608 + k0 + cq);
      uint4 a0 = src[0], a1 = src[1];
      *(uint4*)&As[r*72 + cq]     = a0;
      *(uint4*)&As[r*72 + cq + 8] = a1;
    }
    {
      const float* src = W + (size_t)(n0 + r)*4608 + k0 + cq;
      float4 f0 = *(const float4*)src,       f1 = *(const float4*)(src + 4);
      float4 f2 = *(const float4*)(src + 8), f3 = *(const float4*)(src + 12);
      uint4 v0, v1;
      v0.x = pack_bf2(f0.x,f0.y); v0.y = pack_bf2(f0.z,f0.w);
      v0.z = pack_bf2(f1.x,f1.y); v0.w = pack_bf2(f1.z,f1.w);
      v1.x = pack_bf2(f2.x,f2.y); v1.y = pack_bf2(f2.z,f2.w);
      v1.z = pack_bf2(f3.x,f3.y); v1.w = pack_bf2(f3.z,f3.w);
      *(uint4*)&Wsm[r*72 + cq]     = v0;
      *(uint4*)&Wsm[r*72 + cq + 8] = v1;
    }
    __syncthreads();
    #pragma unroll
    for (int kk = 0; kk < 2; ++kk) {
      union { bf16x8_t v; uint4 u; } bf;
      bf.u = *(const uint4*)&As[(wv*16 + (lane & 15))*72 + kk*32 + (lane >> 4)*8];
      #pragma unroll
      for (int tt = 0; tt < 4; ++tt) {
        union { bf16x8_t v; uint4 u; } af;
        af.u = *(const uint4*)&Wsm[(tt*16 + (lane & 15))*72 + kk*32 + (lane >> 4)*8];
        acc[tt] = __builtin_amdgcn_mfma_f32_16x16x32_bf16(af.v, bf.v, acc[tt], 0, 0, 0);
      }
    }
  }
  {
    int m = m0 + wv*16 + (lane & 15);
    int q4 = lane >> 4;
    #pragma unroll
    for (int tt = 0; tt < 4; ++tt) {
      #pragma unroll
      for (int rg = 0; rg < 4; ++rg) {
        int n = n0 + tt*16 + q4*4 + rg;
        C[(size_t)m*512 + n] = fmaxf(acc[tt][rg] + bias[n], 0.f);
      }
    }
  }
}

// ---------------- GEMM fp32 (gi only): C[M][N] = A*B^T + bias ----------------
template<bool RELU>
__global__ __launch_bounds__(256) void gemm_k(const float* __restrict__ A, const float* __restrict__ B,
                                              const float* __restrict__ bias, float* __restrict__ C,
                                              int M, int N, int K) {
  __shared__ float As[32][33];
  __shared__ float Bs[32][33];
  const int tid = threadIdx.x;
  const int tx = tid & 15, ty = tid >> 4;
  const int m0 = blockIdx.y * 32, n0 = blockIdx.x * 32;
  const int lr = tid >> 3;
  const int lc = (tid & 7) * 4;
  float acc00 = 0.f, acc01 = 0.f, acc10 = 0.f, acc11 = 0.f;
  for (int k0 = 0; k0 < K; k0 += 32) {
    float4 a4 = *(const float4*)(A + (size_t)(m0 + lr)*K + k0 + lc);
    float4 b4 = *(const float4*)(B + (size_t)(n0 + lr)*K + k0 + lc);
    __syncthreads();
    As[lc+0][lr] = a4.x; As[lc+1][lr] = a4.y; As[lc+2][lr] = a4.z; As[lc+3][lr] = a4.w;
    Bs[lc+0][lr] = b4.x; Bs[lc+1][lr] = b4.y; Bs[lc+2][lr] = b4.z; Bs[lc+3][lr] = b4.w;
    __syncthreads();
    #pragma unroll
    for (int kk = 0; kk < 32; ++kk) {
      float a0 = As[kk][ty*2], a1 = As[kk][ty*2+1];
      float b0 = Bs[kk][tx*2], b1 = Bs[kk][tx*2+1];
      acc00 += a0*b0; acc01 += a0*b1; acc10 += a1*b0; acc11 += a1*b1;
    }
  }
  int m = m0 + ty*2, n = n0 + tx*2;
  float bi0 = bias[n], bi1 = bias[n+1];
  float c00 = acc00 + bi0, c01 = acc01 + bi1, c10 = acc10 + bi0, c11 = acc11 + bi1;
  if (RELU) {
    c00 = fmaxf(c00, 0.f); c01 = fmaxf(c01, 0.f);
    c10 = fmaxf(c10, 0.f); c11 = fmaxf(c11, 0.f);
  }
  C[(size_t)m*N + n] = c00;       C[(size_t)m*N + n + 1] = c01;
  C[(size_t)(m+1)*N + n] = c10;   C[(size_t)(m+1)*N + n + 1] = c11;
}

// ---------------- GRU persistent kernel v9: 8 blocks x 512 threads ----------------
// Each block owns 64 H-cols (192 w_hh rows, all 3 gates) with weights register-
// resident (wfr[2][16], waves 0-3 carry 2 row-tiles, waves 4-7 carry 1).
// Per-step peer exchange: publisher stores PRE-MASKED bf16-packed h (512 u32 per
// slice, agent-scope atomics -> LLC), flag after barrier-drained publish.
// Readers poll 8 flags, u64-copy 7 peer slices straight into LDS (no convert).
// Non-critical stores (outs, own hp/hbf) moved AFTER the flag store.
#define GRU_NB 8
__global__ __launch_bounds__(512) void gru_k(const float* __restrict__ gi, const float* __restrict__ states,
    const float* __restrict__ masks, const float* __restrict__ w_hh, const float* __restrict__ b_hh,
    float* __restrict__ outs, unsigned int* __restrict__ hbuf, int* __restrict__ flags,
    float* __restrict__ states_out) {
  __shared__ __align__(16) unsigned short hbf[16*520];  // full h (bf16, masked), stride 520 -> 16B rows
  __shared__ float hp_s[16*64];                         // own-slice h_prev (fp32, masked)
  __shared__ float gh_s[192*17];
  __shared__ float bhs[192];
  __shared__ float mask_s[512];
  const int b    = blockIdx.x;
  const int tid  = threadIdx.x;
  const int lane = tid & 63;
  const int wv   = tid >> 6;          // 0..7
  const int jbase = b * 64;
  const int gn = tid >> 5;            // batch row 0..15
  const int gj = (tid & 31) * 2;      // adjacent j-pair 0..62

  mask_s[tid < 512 ? tid : 0] = masks[tid < 512 ? tid : 0];
  if (tid < 192) bhs[tid] = b_hh[(tid >> 6)*512 + jbase + (tid & 63)];

  // weights: wave wv -> tiles {wv, wv+8 (if <12)}; tile tt: gate tt>>2, j-off (tt&3)*16
  bf16x8_t wfr[2][16];
  {
    int r = lane & 15, q = lane >> 4;
    #pragma unroll
    for (int ti = 0; ti < 2; ++ti) {
      int tt = wv + ti*8;
      if (tt < 12) {
        int g = tt >> 2, jt = (tt & 3) * 16;
        const float* wrow = w_hh + (size_t)(g*512 + jbase + jt + r)*512 + q*8;
        #pragma unroll
        for (int ks = 0; ks < 16; ++ks) {
          float4 f0 = *(const float4*)(wrow + ks*32);
          float4 f1 = *(const float4*)(wrow + ks*32 + 4);
          bf16x8_t v;
          v[0] = (__bf16)f0.x; v[1] = (__bf16)f0.y; v[2] = (__bf16)f0.z; v[3] = (__bf16)f0.w;
          v[4] = (__bf16)f1.x; v[5] = (__bf16)f1.y; v[6] = (__bf16)f1.z; v[7] = (__bf16)f1.w;
          wfr[ti][ks] = v;
        }
      }
    }
  }
  __syncthreads();

  for (int t = 0; t < 32; ++t) {
    // gi loads first: overlap with flag wait
    const float* gip = gi + (size_t)(t*16 + gn)*1536 + jbase + gj;
    float2 giR = *(const float2*)(gip);
    float2 giZ = *(const float2*)(gip + 512);
    float2 giN = *(const float2*)(gip + 1024);

    if (t == 0) {
      for (int i = tid; i < 4096; i += 512) {
        int nn = i >> 8, kp = (i & 255) * 2;
        float m = mask_s[nn];
        float f0 = states[nn*512 + kp], f1 = states[nn*512 + kp + 1];
        *(unsigned int*)&hbf[nn*520 + kp] = pack_bf2(f0*m, f1*m);
      }
      {
        float m0 = mask_s[gn];
        hp_s[gn*64 + gj]     = states[gn*512 + jbase + gj] * m0;
        hp_s[gn*64 + gj + 1] = states[gn*512 + jbase + gj + 1] * m0;
      }
      __syncthreads();
    } else {
      // wait for all 8 peers to have published step-t data
      {
        int done = 0;
        while (!done) {
          int ok = 1;
          if (lane < 8) {
            int v = __hip_atomic_load(&flags[lane*16], __ATOMIC_RELAXED, __HIP_MEMORY_SCOPE_AGENT);
            ok = (v >= t);
          }
          done = __all(ok);
          if (!done) __builtin_amdgcn_s_sleep(1);
        }
      }
      // copy 7 peer slices (pre-masked bf16) into LDS: 1792 u64 words
      {
        const unsigned long long* hsrc =
            (const unsigned long long*)(hbuf + (t & 1)*4096);
        #pragma unroll
        for (int idx = tid; idx < 1792; idx += 512) {
          int s  = idx >> 8;                // 0..6
          int p  = s + (s >= b);            // skip own slice
          int rem = idx & 255;
          int nn = rem >> 4;
          int jw = rem & 15;                // u64 word within 64-col row
          unsigned long long u = __hip_atomic_load(hsrc + p*256 + nn*16 + jw,
                                 __ATOMIC_RELAXED, __HIP_MEMORY_SCOPE_AGENT);
          *(unsigned long long*)&hbf[nn*520 + p*64 + jw*4] = u;
        }
      }
      __syncthreads();
    }

    // MFMA: gh = w_hh(slice) * h
    {
      int r = lane & 15, q = lane >> 4;
      const unsigned short* hrow = &hbf[r*520 + q*8];
      #pragma unroll
      for (int ti = 0; ti < 2; ++ti) {
        int tt = wv + ti*8;
        if (tt < 12) {
          f32x4_t acc = {0.f, 0.f, 0.f, 0.f};
          #pragma unroll
          for (int ks = 0; ks < 16; ++ks) {
            union { bf16x8_t v; uint4 u; } fb;
            fb.u = *(const uint4*)(hrow + ks*32);
            acc = __builtin_amdgcn_mfma_f32_16x16x32_bf16(wfr[ti][ks], fb.v, acc, 0, 0, 0);
          }
          int g = tt >> 2, jt = (tt & 3) * 16;
          #pragma unroll
          for (int rg = 0; rg < 4; ++rg)
            gh_s[(g*64 + jt + q*4 + rg)*17 + r] = acc[rg];
        }
      }
    }
    __syncthreads();

    // gates: 2 adjacent j per thread, publish -> barrier -> flag -> cold stores
    {
      float ghr0 = gh_s[(gj    )*17 + gn] + bhs[gj];
      float ghr1 = gh_s[(gj + 1)*17 + gn] + bhs[gj + 1];
      float ghz0 = gh_s[(64 + gj)*17 + gn] + bhs[64 + gj];
      float ghz1 = gh_s[(65 + gj)*17 + gn] + bhs[65 + gj];
      float ghn0 = gh_s[(128 + gj)*17 + gn] + bhs[128 + gj];
      float ghn1 = gh_s[(129 + gj)*17 + gn] + bhs[129 + gj];
      float r0 = 1.f / (1.f + expf(-(giR.x + ghr0)));
      float r1 = 1.f / (1.f + expf(-(giR.y + ghr1)));
      float z0 = 1.f / (1.f + expf(-(giZ.x + ghz0)));
      float z1 = 1.f / (1.f + expf(-(giZ.y + ghz1)));
      float n0 = tanhf(giN.x + r0*ghn0);
      float n1 = tanhf(giN.y + r1*ghn1);
      float hp0 = hp_s[gn*64 + gj];
      float hp1 = hp_s[gn*64 + gj + 1];
      float hn0 = (1.f - z0)*n0 + z0*hp0;
      float hn1 = (1.f - z1)*n1 + z1*hp1;
      float mnext = (t < 31) ? mask_s[(t+1)*16 + gn] : 0.f;
      float hm0 = hn0 * mnext, hm1 = hn1 * mnext;
      if (t < 31) {
        // critical-path publish: pre-masked bf16 pair
        __hip_atomic_store(hbuf + ((t+1)&1)*4096 + b*512 + gn*32 + (gj >> 1),
                           pack_bf2(hm0, hm1), __ATOMIC_RELAXED, __HIP_MEMORY_SCOPE_AGENT);
      }
      __syncthreads();   // drains all threads' publishes (vmcnt(0)) before flag
      if (t < 31) {
        if (tid == 0)
          __hip_atomic_store(&flags[b*16], t + 1, __ATOMIC_RELAXED, __HIP_MEMORY_SCOPE_AGENT);
        // cold stores off the inter-block critical path
        *(float2*)&outs[(size_t)(t*16 + gn)*512 + jbase + gj] = make_float2(hn0, hn1);
        hp_s[gn*64 + gj]     = hm0;
        hp_s[gn*64 + gj + 1] = hm1;
        *(unsigned int*)&hbf[gn*520 + jbase + gj] = pack_bf2(hm0, hm1);
      } else {
        *(float2*)&outs[(size_t)(t*16 + gn)*512 + jbase + gj] = make_float2(hn0, hn1);
        *(float2*)&states_out[gn*512 + jbase + gj] = make_float2(hn0, hn1);
      }
    }
  }
}

// ---------------- heads ----------------
__global__ __launch_bounds__(256) void heads_k(const float* __restrict__ xs, const int* __restrict__ action,
    const float* __restrict__ aw, const float* __restrict__ ab,
    const float* __restrict__ cw, const float* __restrict__ cb, float* __restrict__ out) {
  int row  = blockIdx.x * 4 + (threadIdx.x >> 6);
  int lane = threadIdx.x & 63;
  const float* xr = xs + (size_t)row * 512;
  float acc[7];
  #pragma unroll
  for (int a = 0; a < 7; ++a) acc[a] = 0.f;
  #pragma unroll
  for (int kb = 0; kb < 8; ++kb) {
    int k = kb*64 + lane;
    float xv = xr[k];
    #pragma unroll
    for (int a = 0; a < 6; ++a) acc[a] += xv * aw[a*512 + k];
    acc[6] += xv * cw[k];
  }
  #pragma unroll
  for (int off = 32; off > 0; off >>= 1) {
    #pragma unroll
    for (int a = 0; a < 7; ++a) acc[a] += __shfl_down(acc[a], off);
  }
  if (lane == 0) {
    float lg[6];
    #pragma unroll
    for (int a = 0; a < 6; ++a) lg[a] = acc[a] + ab[a];
    float mx = lg[0];
    #pragma unroll
    for (int a = 1; a < 6; ++a) mx = fmaxf(mx, lg[a]);
    float se = 0.f;
    #pragma unroll
    for (int a = 0; a < 6; ++a) se += expf(lg[a] - mx);
    float lse = mx + logf(se);
    float ent = 0.f;
    #pragma unroll
    for (int a = 0; a < 6; ++a) { float lp = lg[a] - lse; ent -= expf(lp)*lp; }
    int ai = action[row];
    out[row]        = acc[6] + cb[0];
    out[512  + row] = lg[ai] - lse;
    out[1024 + row] = ent;
  }
}

extern "C" void kernel_launch(void* const* d_in, const int* in_sizes, int n_in,
                              void* d_out, int out_size, void* d_ws, size_t ws_size,
                              hipStream_t stream) {
  const float* x      = (const float*)d_in[0];
  const float* states = (const float*)d_in[1];
  const float* masks  = (const float*)d_in[2];
  const int*   action = (const int*)d_in[3];
  const float* c1w = (const float*)d_in[4];
  const float* c1b = (const float*)d_in[5];
  const float* c2w = (const float*)d_in[6];
  const float* c2b = (const float*)d_in[7];
  const float* c3w = (const float*)d_in[8];
  const float* c3b = (const float*)d_in[9];
  const float* fcw = (const float*)d_in[10];
  const float* fcb = (const float*)d_in[11];
  const float* wih = (const float*)d_in[12];
  const float* whh = (const float*)d_in[13];
  const float* bih = (const float*)d_in[14];
  const float* bhh = (const float*)d_in[15];
  const float* aw  = (const float*)d_in[16];
  const float* ab  = (const float*)d_in[17];
  const float* cw  = (const float*)d_in[18];
  const float* cb  = (const float*)d_in[19];
  (void)in_sizes; (void)n_in; (void)out_size; (void)ws_size;

  float* ws = (float*)d_ws;
  unsigned short* o1b = (unsigned short*)ws;     // conv1 out bf16
  float* o2    = ws + 14745600;                  // conv2 out fp32
  unsigned short* o3b = (unsigned short*)ws;     // conv3 out bf16 (reuses o1b region after conv2)
  float* xs    = ws + 2359296;
  float* gibuf = ws + 2621440;
  float* outs  = ws + 3407872;
  unsigned int* hbuf = (unsigned int*)(ws + 3670016);   // 2 x 4096 u32 (bf16-packed h slices)
  int*   flags = (int*)(ws + 3686400);
  float* out   = (float*)d_out;

  conv1_mfma<<<7200, 256, 0, stream>>>(x, c1w, c1b, o1b);
  conv2_mfma<<<1568, 256, 0, stream>>>(o1b, c2w, c2b, o2);
  conv3_k<<<dim3(144, 2), 256, 0, stream>>>(o2, c3w, c3b, o3b);
  fc_mfma<<<dim3(8, 8), 256, 0, stream>>>(o3b, fcw, fcb, xs);
  gemm_k<false><<<dim3(48, 16), 256, 0, stream>>>(xs, wih, bih, gibuf, 512, 1536, 512);
  hipMemsetAsync(flags, 0, 1024 * sizeof(int), stream);
  gru_k<<<GRU_NB, 512, 0, stream>>>(gibuf, states, masks, whh, bhh, outs, hbuf, flags, out + 1536);
  heads_k<<<128, 256, 0, stream>>>(outs, action, aw, ab, cw, cb, out);
}

// Round 2
// 638.586 us; speedup vs baseline: 1.1300x; 1.0958x over previous
//
#include <hip/hip_runtime.h>
#include <hip/hip_bf16.h>

// Problem constants
// inputs [512][4][124][124], conv1 w[32][4][8][8] s4 -> [512][32][30][30] (bf16, MFMA)
// conv2 w[64][32][4][4] s2 -> [512][64][14][14]   (MFMA implicit GEMM)
// conv3 w[32][64][3][3] s1 -> [512][32][12][12] bf16 -> flat 4608
// fc [512,4608] -> xs [512][512] relu  (MFMA)
// gi = xs @ w_ih^T + b_ih : [512][1536]
// GRU T=32, N=16, H=512 ; heads A=6
// d_out: value[512] | alp[512] | ent[512] | states_out[16*512]

typedef __bf16 bf16x8_t __attribute__((ext_vector_type(8)));
typedef float  f32x4_t  __attribute__((ext_vector_type(4)));

__device__ __forceinline__ unsigned int pack_bf2(float a, float b) {
  union { __bf16 h[2]; unsigned int u; } c;
  c.h[0] = (__bf16)a; c.h[1] = (__bf16)b;
  return c.u;
}
__device__ __forceinline__ unsigned short f2bf(float x) {
  union { __bf16 h; unsigned short s; } c; c.h = (__bf16)x; return c.s;
}

// ---------------- conv1 v2: slab-staged bf16 MFMA, no im2col ----------------
// Block = (image n, half): 15 output rows = 450 px. Stage 4ch x 64 rows x 124
// cols fp32 -> bf16 LDS image (row pad 140 shorts: b64 frag reads 2-lane/bank).
// K = c*64+ky*8+kx: a B-fragment's 8 elements = 8 contiguous px of one image
// row -> fragments read straight from the raw image, no im2col.
// 31 coalesced float4 loads/thread, independent -> deep MLP (256-VGPR budget).
__global__ __launch_bounds__(256, 2) void conv1_mfma(const float* __restrict__ x,
        const float* __restrict__ w, const float* __restrict__ bias,
        unsigned short* __restrict__ out) {
  __shared__ __align__(16) unsigned short img[4*64*140];   // 71.7 KB
  const int tid  = threadIdx.x;
  const int lane = tid & 63;
  const int wv   = tid >> 6;
  const int n    = blockIdx.x >> 1;
  const int half = blockIdx.x & 1;
  const int y0   = half * 60;        // input rows y0..y0+63 cover output rows half*15..half*15+14
  // ---- staging: whole 4x64x124 slab, single coalesced pass ----
  {
    #pragma unroll
    for (int it = 0; it < 31; ++it) {
      int i  = it*256 + tid;          // [0, 4*64*31)
      int c  = i / 1984;              // 1984 = 64*31
      int r  = i - c*1984;
      int y  = r / 31;
      int xq = r - y*31;
      const float4 f = *(const float4*)(x + ((size_t)(n*4 + c)*124 + (y0 + y))*124 + xq*4);
      uint2 v; v.x = pack_bf2(f.x, f.y); v.y = pack_bf2(f.z, f.w);
      *(uint2*)&img[(c*64 + y)*140 + xq*4] = v;
    }
  }
  // ---- weights -> A-frags (2 oc-tiles x 8 ksteps), register-resident ----
  bf16x8_t wfr[2][8];
  {
    int m = lane & 15, q = lane >> 4;
    #pragma unroll
    for (int tt = 0; tt < 2; ++tt) {
      const float* wrow = w + (size_t)(tt*16 + m)*256 + q*8;
      #pragma unroll
      for (int ks = 0; ks < 8; ++ks) {
        float4 f0 = *(const float4*)(wrow + ks*32);
        float4 f1 = *(const float4*)(wrow + ks*32 + 4);
        bf16x8_t v;
        v[0]=(__bf16)f0.x; v[1]=(__bf16)f0.y; v[2]=(__bf16)f0.z; v[3]=(__bf16)f0.w;
        v[4]=(__bf16)f1.x; v[5]=(__bf16)f1.y; v[6]=(__bf16)f1.z; v[7]=(__bf16)f1.w;
        wfr[tt][ks] = v;
      }
    }
  }
  __syncthreads();
  // ---- compute: 29 px-tiles of 16, round-robin over waves ----
  const int m = lane & 15, q = lane >> 4;
  int rb[8];                           // img row base per k-step: c*64 + ky
  #pragma unroll
  for (int ks = 0; ks < 8; ++ks) {
    int kk = ks*32 + q*8;
    rb[ks] = (kk >> 6)*64 + ((kk >> 3) & 7);
  }
  const float sc = 1.0f / 255.0f;
  for (int tile = wv; tile < 29; tile += 4) {
    int pl = tile*16 + m;
    int ok = pl < 450;
    if (!ok) pl = 449;
    int t = pl / 30, opx = pl - t*30;  // local output row / col
    int t4 = t*4, opx4 = opx*4;
    f32x4_t acc0 = {0.f,0.f,0.f,0.f}, acc1 = {0.f,0.f,0.f,0.f};
    #pragma unroll
    for (int ks = 0; ks < 8; ++ks) {
      const unsigned short* p = &img[(rb[ks] + t4)*140 + opx4];
      union { bf16x8_t v; uint2 u[2]; } fb;
      fb.u[0] = *(const uint2*)p;
      fb.u[1] = *(const uint2*)(p + 4);
      acc0 = __builtin_amdgcn_mfma_f32_16x16x32_bf16(wfr[0][ks], fb.v, acc0, 0, 0, 0);
      acc1 = __builtin_amdgcn_mfma_f32_16x16x32_bf16(wfr[1][ks], fb.v, acc1, 0, 0, 0);
    }
    if (ok) {
      int opy = half*15 + t;
      size_t obase = (size_t)n*32*900 + opy*30 + opx;
      #pragma unroll
      for (int rg = 0; rg < 4; ++rg) {
        int oc0 = q*4 + rg;
        out[obase + (size_t)oc0*900]      = f2bf(fmaxf(acc0[rg]*sc + bias[oc0], 0.f));
        out[obase + (size_t)(oc0+16)*900] = f2bf(fmaxf(acc1[rg]*sc + bias[oc0+16], 0.f));
      }
    }
  }
}

// ---------------- conv2: bf16 MFMA implicit GEMM (verified r9) ----------------
__global__ __launch_bounds__(256) void conv2_mfma(const unsigned short* __restrict__ in,
        const float* __restrict__ w, const float* __restrict__ bias,
        float* __restrict__ out) {
  __shared__ __align__(16) unsigned short pt[64*520];   // 65 KB
  const int tid  = threadIdx.x;
  const int lane = tid & 63;
  const int wv   = tid >> 6;
  const int px0  = blockIdx.x * 64;
  {
    int px = px0 + lane;
    int n = px / 196, q = px % 196;
    int oy = q / 14, ox = q % 14;
    const unsigned short* base = in + ((size_t)(n*32)*30 + oy*2)*30 + ox*2;
    #pragma unroll 4
    for (int it = 0; it < 32; ++it) {
      int c  = wv*8 + (it >> 2);
      int ky = it & 3;
      const unsigned short* src = base + (c*30 + ky)*30;
      unsigned int a0 = *(const unsigned int*)(src);
      unsigned int a1 = *(const unsigned int*)(src + 2);
      *(uint2*)&pt[lane*520 + c*16 + ky*4] = make_uint2(a0, a1);
    }
  }
  bf16x8_t wfr[16];
  {
    int m = lane & 15, q = lane >> 4;
    const float* wrow = w + (size_t)(wv*16 + m)*512 + q*8;
    #pragma unroll
    for (int ks = 0; ks < 16; ++ks) {
      float4 f0 = *(const float4*)(wrow + ks*32);
      float4 f1 = *(const float4*)(wrow + ks*32 + 4);
      bf16x8_t v;
      v[0] = (__bf16)f0.x; v[1] = (__bf16)f0.y; v[2] = (__bf16)f0.z; v[3] = (__bf16)f0.w;
      v[4] = (__bf16)f1.x; v[5] = (__bf16)f1.y; v[6] = (__bf16)f1.z; v[7] = (__bf16)f1.w;
      wfr[ks] = v;
    }
  }
  __syncthreads();
  f32x4_t acc[4];
  #pragma unroll
  for (int pxt = 0; pxt < 4; ++pxt) {
    f32x4_t a = {0.f, 0.f, 0.f, 0.f};
    const unsigned short* prow = &pt[(pxt*16 + (lane & 15))*520 + (lane >> 4)*8];
    #pragma unroll
    for (int ks = 0; ks < 16; ++ks) {
      union { bf16x8_t v; uint4 u; } fb;
      fb.u = *(const uint4*)(prow + ks*32);
      a = __builtin_amdgcn_mfma_f32_16x16x32_bf16(wfr[ks], fb.v, a, 0, 0, 0);
    }
    acc[pxt] = a;
  }
  {
    int q4 = lane >> 4;
    float b4[4];
    #pragma unroll
    for (int rg = 0; rg < 4; ++rg) b4[rg] = bias[wv*16 + q4*4 + rg];
    #pragma unroll
    for (int pxt = 0; pxt < 4; ++pxt) {
      int px = px0 + pxt*16 + (lane & 15);
      int n = px / 196, q = px % 196;
      #pragma unroll
      for (int rg = 0; rg < 4; ++rg) {
        int oc = wv*16 + q4*4 + rg;
        out[((size_t)n*64 + oc)*196 + q] = fmaxf(acc[pxt][rg] + b4[rg], 0.f);
      }
    }
  }
}

// ---------------- conv3 (fp32 compute, bf16 output for fc MFMA) ----------------
__global__ __launch_bounds__(256) void conv3_k(const float* __restrict__ in,
        const float* __restrict__ w, const float* __restrict__ bias,
        unsigned short* __restrict__ out) {
  __shared__ float wsT[9216];               // [(c*3+ky)*3+kx][oc]
  int och0 = blockIdx.y * 16;
  for (int i = threadIdx.x; i < 9216; i += 256) {
    int oc = i & 15, rest = i >> 4;
    int kx = rest % 3, t2 = rest / 3;
    int ky = t2 % 3, c = t2 / 3;
    wsT[i] = w[(size_t)(och0 + oc)*576 + c*9 + ky*3 + kx];
  }
  __syncthreads();
  int pidx = blockIdx.x * 256 + threadIdx.x;   // [0, 512*72)
  int n = pidx / 72;
  int q = pidx % 72;
  int oy0 = q / 12, ox0 = q % 12;
  int q1 = q + 72;
  int oy1 = q1 / 12, ox1 = q1 % 12;
  float acc0[16], acc1[16];
  #pragma unroll
  for (int oc = 0; oc < 16; ++oc) { float bb = bias[och0 + oc]; acc0[oc] = bb; acc1[oc] = bb; }
  for (int c = 0; c < 64; ++c) {
    #pragma unroll
    for (int ky = 0; ky < 3; ++ky) {
      const float* r0 = in + ((n*64 + c)*14 + oy0 + ky)*14 + ox0;
      const float* r1 = in + ((n*64 + c)*14 + oy1 + ky)*14 + ox1;
      float v0[3] = {r0[0], r0[1], r0[2]};
      float v1[3] = {r1[0], r1[1], r1[2]};
      #pragma unroll
      for (int kx = 0; kx < 3; ++kx) {
        const float4* wp = (const float4*)&wsT[((c*3 + ky)*3 + kx)*16];
        float4 wA = wp[0], wB = wp[1], wC = wp[2], wD = wp[3];
        float a = v0[kx], b = v1[kx];
        acc0[0] += a*wA.x; acc0[1] += a*wA.y; acc0[2]  += a*wA.z; acc0[3]  += a*wA.w;
        acc0[4] += a*wB.x; acc0[5] += a*wB.y; acc0[6]  += a*wB.z; acc0[7]  += a*wB.w;
        acc0[8] += a*wC.x; acc0[9] += a*wC.y; acc0[10] += a*wC.z; acc0[11] += a*wC.w;
        acc0[12]+= a*wD.x; acc0[13]+= a*wD.y; acc0[14] += a*wD.z; acc0[15] += a*wD.w;
        acc1[0] += b*wA.x; acc1[1] += b*wA.y; acc1[2]  += b*wA.z; acc1[3]  += b*wA.w;
        acc1[4] += b*wB.x; acc1[5] += b*wB.y; acc1[6]  += b*wB.z; acc1[7]  += b*wB.w;
        acc1[8] += b*wC.x; acc1[9] += b*wC.y; acc1[10] += b*wC.z; acc1[11] += b*wC.w;
        acc1[12]+= b*wD.x; acc1[13]+= b*wD.y; acc1[14] += b*wD.z; acc1[15] += b*wD.w;
      }
    }
  }
  #pragma unroll
  for (int oc = 0; oc < 16; ++oc) {
    out[(n*32 + och0 + oc)*144 + q]      = f2bf(fmaxf(acc0[oc], 0.f));
    out[(n*32 + och0 + oc)*144 + q + 72] = f2bf(fmaxf(acc1[oc], 0.f));
  }
}

// ---------------- fc: bf16 MFMA GEMM ----------------
__global__ __launch_bounds__(256) void fc_mfma(const unsigned short* __restrict__ A,
        const float* __restrict__ W, const float* __restrict__ bias,
        float* __restrict__ C) {
  __shared__ __align__(16) unsigned short As[64*72];
  __shared__ __align__(16) unsigned short Wsm[64*72];
  const int tid  = threadIdx.x;
  const int lane = tid & 63;
  const int wv   = tid >> 6;
  const int m0 = blockIdx.y * 64, n0 = blockIdx.x * 64;
  const int r  = tid >> 2;
  const int cq = (tid & 3) * 16;
  f32x4_t acc[4] = {{0,0,0,0},{0,0,0,0},{0,0,0,0},{0,0,0,0}};
  for (int k0 = 0; k0 < 4608; k0 += 64) {
    __syncthreads();
    {
      const uint4* src = (const uint4*)(A + (size_t)(m0 + r)*4608 + k0 + cq);
      uint4 a0 = src[0], a1 = src[1];
      *(uint4*)&As[r*72 + cq]     = a0;
      *(uint4*)&As[r*72 + cq + 8] = a1;
    }
    {
      const float* src = W + (size_t)(n0 + r)*4608 + k0 + cq;
      float4 f0 = *(const float4*)src,       f1 = *(const float4*)(src + 4);
      float4 f2 = *(const float4*)(src + 8), f3 = *(const float4*)(src + 12);
      uint4 v0, v1;
      v0.x = pack_bf2(f0.x,f0.y); v0.y = pack_bf2(f0.z,f0.w);
      v0.z = pack_bf2(f1.x,f1.y); v0.w = pack_bf2(f1.z,f1.w);
      v1.x = pack_bf2(f2.x,f2.y); v1.y = pack_bf2(f2.z,f2.w);
      v1.z = pack_bf2(f3.x,f3.y); v1.w = pack_bf2(f3.z,f3.w);
      *(uint4*)&Wsm[r*72 + cq]     = v0;
      *(uint4*)&Wsm[r*72 + cq + 8] = v1;
    }
    __syncthreads();
    #pragma unroll
    for (int kk = 0; kk < 2; ++kk) {
      union { bf16x8_t v; uint4 u; } bf;
      bf.u = *(const uint4*)&As[(wv*16 + (lane & 15))*72 + kk*32 + (lane >> 4)*8];
      #pragma unroll
      for (int tt = 0; tt < 4; ++tt) {
        union { bf16x8_t v; uint4 u; } af;
        af.u = *(const uint4*)&Wsm[(tt*16 + (lane & 15))*72 + kk*32 + (lane >> 4)*8];
        acc[tt] = __builtin_amdgcn_mfma_f32_16x16x32_bf16(af.v, bf.v, acc[tt], 0, 0, 0);
      }
    }
  }
  {
    int m = m0 + wv*16 + (lane & 15);
    int q4 = lane >> 4;
    #pragma unroll
    for (int tt = 0; tt < 4; ++tt) {
      #pragma unroll
      for (int rg = 0; rg < 4; ++rg) {
        int n = n0 + tt*16 + q4*4 + rg;
        C[(size_t)m*512 + n] = fmaxf(acc[tt][rg] + bias[n], 0.f);
      }
    }
  }
}

// ---------------- GEMM fp32 (gi only): C[M][N] = A*B^T + bias ----------------
template<bool RELU>
__global__ __launch_bounds__(256) void gemm_k(const float* __restrict__ A, const float* __restrict__ B,
                                              const float* __restrict__ bias, float* __restrict__ C,
                                              int M, int N, int K) {
  __shared__ float As[32][33];
  __shared__ float Bs[32][33];
  const int tid = threadIdx.x;
  const int tx = tid & 15, ty = tid >> 4;
  const int m0 = blockIdx.y * 32, n0 = blockIdx.x * 32;
  const int lr = tid >> 3;
  const int lc = (tid & 7) * 4;
  float acc00 = 0.f, acc01 = 0.f, acc10 = 0.f, acc11 = 0.f;
  for (int k0 = 0; k0 < K; k0 += 32) {
    float4 a4 = *(const float4*)(A + (size_t)(m0 + lr)*K + k0 + lc);
    float4 b4 = *(const float4*)(B + (size_t)(n0 + lr)*K + k0 + lc);
    __syncthreads();
    As[lc+0][lr] = a4.x; As[lc+1][lr] = a4.y; As[lc+2][lr] = a4.z; As[lc+3][lr] = a4.w;
    Bs[lc+0][lr] = b4.x; Bs[lc+1][lr] = b4.y; Bs[lc+2][lr] = b4.z; Bs[lc+3][lr] = b4.w;
    __syncthreads();
    #pragma unroll
    for (int kk = 0; kk < 32; ++kk) {
      float a0 = As[kk][ty*2], a1 = As[kk][ty*2+1];
      float b0 = Bs[kk][tx*2], b1 = Bs[kk][tx*2+1];
      acc00 += a0*b0; acc01 += a0*b1; acc10 += a1*b0; acc11 += a1*b1;
    }
  }
  int m = m0 + ty*2, n = n0 + tx*2;
  float bi0 = bias[n], bi1 = bias[n+1];
  float c00 = acc00 + bi0, c01 = acc01 + bi1, c10 = acc10 + bi0, c11 = acc11 + bi1;
  if (RELU) {
    c00 = fmaxf(c00, 0.f); c01 = fmaxf(c01, 0.f);
    c10 = fmaxf(c10, 0.f); c11 = fmaxf(c11, 0.f);
  }
  C[(size_t)m*N + n] = c00;       C[(size_t)m*N + n + 1] = c01;
  C[(size_t)(m+1)*N + n] = c10;   C[(size_t)(m+1)*N + n + 1] = c11;
}

// ---------------- GRU persistent kernel v9: 8 blocks x 512 threads ----------------
#define GRU_NB 8
__global__ __launch_bounds__(512) void gru_k(const float* __restrict__ gi, const float* __restrict__ states,
    const float* __restrict__ masks, const float* __restrict__ w_hh, const float* __restrict__ b_hh,
    float* __restrict__ outs, unsigned int* __restrict__ hbuf, int* __restrict__ flags,
    float* __restrict__ states_out) {
  __shared__ __align__(16) unsigned short hbf[16*520];  // full h (bf16, masked), stride 520 -> 16B rows
  __shared__ float hp_s[16*64];                         // own-slice h_prev (fp32, masked)
  __shared__ float gh_s[192*17];
  __shared__ float bhs[192];
  __shared__ float mask_s[512];
  const int b    = blockIdx.x;
  const int tid  = threadIdx.x;
  const int lane = tid & 63;
  const int wv   = tid >> 6;          // 0..7
  const int jbase = b * 64;
  const int gn = tid >> 5;            // batch row 0..15
  const int gj = (tid & 31) * 2;      // adjacent j-pair 0..62

  mask_s[tid < 512 ? tid : 0] = masks[tid < 512 ? tid : 0];
  if (tid < 192) bhs[tid] = b_hh[(tid >> 6)*512 + jbase + (tid & 63)];

  // weights: wave wv -> tiles {wv, wv+8 (if <12)}; tile tt: gate tt>>2, j-off (tt&3)*16
  bf16x8_t wfr[2][16];
  {
    int r = lane & 15, q = lane >> 4;
    #pragma unroll
    for (int ti = 0; ti < 2; ++ti) {
      int tt = wv + ti*8;
      if (tt < 12) {
        int g = tt >> 2, jt = (tt & 3) * 16;
        const float* wrow = w_hh + (size_t)(g*512 + jbase + jt + r)*512 + q*8;
        #pragma unroll
        for (int ks = 0; ks < 16; ++ks) {
          float4 f0 = *(const float4*)(wrow + ks*32);
          float4 f1 = *(const float4*)(wrow + ks*32 + 4);
          bf16x8_t v;
          v[0] = (__bf16)f0.x; v[1] = (__bf16)f0.y; v[2] = (__bf16)f0.z; v[3] = (__bf16)f0.w;
          v[4] = (__bf16)f1.x; v[5] = (__bf16)f1.y; v[6] = (__bf16)f1.z; v[7] = (__bf16)f1.w;
          wfr[ti][ks] = v;
        }
      }
    }
  }
  __syncthreads();

  for (int t = 0; t < 32; ++t) {
    const float* gip = gi + (size_t)(t*16 + gn)*1536 + jbase + gj;
    float2 giR = *(const float2*)(gip);
    float2 giZ = *(const float2*)(gip + 512);
    float2 giN = *(const float2*)(gip + 1024);

    if (t == 0) {
      for (int i = tid; i < 4096; i += 512) {
        int nn = i >> 8, kp = (i & 255) * 2;
        float m = mask_s[nn];
        float f0 = states[nn*512 + kp], f1 = states[nn*512 + kp + 1];
        *(unsigned int*)&hbf[nn*520 + kp] = pack_bf2(f0*m, f1*m);
      }
      {
        float m0 = mask_s[gn];
        hp_s[gn*64 + gj]     = states[gn*512 + jbase + gj] * m0;
        hp_s[gn*64 + gj + 1] = states[gn*512 + jbase + gj + 1] * m0;
      }
      __syncthreads();
    } else {
      {
        int done = 0;
        while (!done) {
          int ok = 1;
          if (lane < 8) {
            int v = __hip_atomic_load(&flags[lane*16], __ATOMIC_RELAXED, __HIP_MEMORY_SCOPE_AGENT);
            ok = (v >= t);
          }
          done = __all(ok);
          if (!done) __builtin_amdgcn_s_sleep(1);
        }
      }
      {
        const unsigned long long* hsrc =
            (const unsigned long long*)(hbuf + (t & 1)*4096);
        #pragma unroll
        for (int idx = tid; idx < 1792; idx += 512) {
          int s  = idx >> 8;                // 0..6
          int p  = s + (s >= b);            // skip own slice
          int rem = idx & 255;
          int nn = rem >> 4;
          int jw = rem & 15;                // u64 word within 64-col row
          unsigned long long u = __hip_atomic_load(hsrc + p*256 + nn*16 + jw,
                                 __ATOMIC_RELAXED, __HIP_MEMORY_SCOPE_AGENT);
          *(unsigned long long*)&hbf[nn*520 + p*64 + jw*4] = u;
        }
      }
      __syncthreads();
    }

    // MFMA: gh = w_hh(slice) * h
    {
      int r = lane & 15, q = lane >> 4;
      const unsigned short* hrow = &hbf[r*520 + q*8];
      #pragma unroll
      for (int ti = 0; ti < 2; ++ti) {
        int tt = wv + ti*8;
        if (tt < 12) {
          f32x4_t acc = {0.f, 0.f, 0.f, 0.f};
          #pragma unroll
          for (int ks = 0; ks < 16; ++ks) {
            union { bf16x8_t v; uint4 u; } fb;
            fb.u = *(const uint4*)(hrow + ks*32);
            acc = __builtin_amdgcn_mfma_f32_16x16x32_bf16(wfr[ti][ks], fb.v, acc, 0, 0, 0);
          }
          int g = tt >> 2, jt = (tt & 3) * 16;
          #pragma unroll
          for (int rg = 0; rg < 4; ++rg)
            gh_s[(g*64 + jt + q*4 + rg)*17 + r] = acc[rg];
        }
      }
    }
    __syncthreads();

    // gates: 2 adjacent j per thread, publish -> barrier -> flag -> cold stores
    {
      float ghr0 = gh_s[(gj    )*17 + gn] + bhs[gj];
      float ghr1 = gh_s[(gj + 1)*17 + gn] + bhs[gj + 1];
      float ghz0 = gh_s[(64 + gj)*17 + gn] + bhs[64 + gj];
      float ghz1 = gh_s[(65 + gj)*17 + gn] + bhs[65 + gj];
      float ghn0 = gh_s[(128 + gj)*17 + gn] + bhs[128 + gj];
      float ghn1 = gh_s[(129 + gj)*17 + gn] + bhs[129 + gj];
      float r0 = 1.f / (1.f + expf(-(giR.x + ghr0)));
      float r1 = 1.f / (1.f + expf(-(giR.y + ghr1)));
      float z0 = 1.f / (1.f + expf(-(giZ.x + ghz0)));
      float z1 = 1.f / (1.f + expf(-(giZ.y + ghz1)));
      float n0 = tanhf(giN.x + r0*ghn0);
      float n1 = tanhf(giN.y + r1*ghn1);
      float hp0 = hp_s[gn*64 + gj];
      float hp1 = hp_s[gn*64 + gj + 1];
      float hn0 = (1.f - z0)*n0 + z0*hp0;
      float hn1 = (1.f - z1)*n1 + z1*hp1;
      float mnext = (t < 31) ? mask_s[(t+1)*16 + gn] : 0.f;
      float hm0 = hn0 * mnext, hm1 = hn1 * mnext;
      if (t < 31) {
        __hip_atomic_store(hbuf + ((t+1)&1)*4096 + b*512 + gn*32 + (gj >> 1),
                           pack_bf2(hm0, hm1), __ATOMIC_RELAXED, __HIP_MEMORY_SCOPE_AGENT);
      }
      __syncthreads();   // drains all threads' publishes (vmcnt(0)) before flag
      if (t < 31) {
        if (tid == 0)
          __hip_atomic_store(&flags[b*16], t + 1, __ATOMIC_RELAXED, __HIP_MEMORY_SCOPE_AGENT);
        *(float2*)&outs[(size_t)(t*16 + gn)*512 + jbase + gj] = make_float2(hn0, hn1);
        hp_s[gn*64 + gj]     = hm0;
        hp_s[gn*64 + gj + 1] = hm1;
        *(unsigned int*)&hbf[gn*520 + jbase + gj] = pack_bf2(hm0, hm1);
      } else {
        *(float2*)&outs[(size_t)(t*16 + gn)*512 + jbase + gj] = make_float2(hn0, hn1);
        *(float2*)&states_out[gn*512 + jbase + gj] = make_float2(hn0, hn1);
      }
    }
  }
}

// ---------------- heads ----------------
__global__ __launch_bounds__(256) void heads_k(const float* __restrict__ xs, const int* __restrict__ action,
    const float* __restrict__ aw, const float* __restrict__ ab,
    const float* __restrict__ cw, const float* __restrict__ cb, float* __restrict__ out) {
  int row  = blockIdx.x * 4 + (threadIdx.x >> 6);
  int lane = threadIdx.x & 63;
  const float* xr = xs + (size_t)row * 512;
  float acc[7];
  #pragma unroll
  for (int a = 0; a < 7; ++a) acc[a] = 0.f;
  #pragma unroll
  for (int kb = 0; kb < 8; ++kb) {
    int k = kb*64 + lane;
    float xv = xr[k];
    #pragma unroll
    for (int a = 0; a < 6; ++a) acc[a] += xv * aw[a*512 + k];
    acc[6] += xv * cw[k];
  }
  #pragma unroll
  for (int off = 32; off > 0; off >>= 1) {
    #pragma unroll
    for (int a = 0; a < 7; ++a) acc[a] += __shfl_down(acc[a], off);
  }
  if (lane == 0) {
    float lg[6];
    #pragma unroll
    for (int a = 0; a < 6; ++a) lg[a] = acc[a] + ab[a];
    float mx = lg[0];
    #pragma unroll
    for (int a = 1; a < 6; ++a) mx = fmaxf(mx, lg[a]);
    float se = 0.f;
    #pragma unroll
    for (int a = 0; a < 6; ++a) se += expf(lg[a] - mx);
    float lse = mx + logf(se);
    float ent = 0.f;
    #pragma unroll
    for (int a = 0; a < 6; ++a) { float lp = lg[a] - lse; ent -= expf(lp)*lp; }
    int ai = action[row];
    out[row]        = acc[6] + cb[0];
    out[512  + row] = lg[ai] - lse;
    out[1024 + row] = ent;
  }
}

extern "C" void kernel_launch(void* const* d_in, const int* in_sizes, int n_in,
                              void* d_out, int out_size, void* d_ws, size_t ws_size,
                              hipStream_t stream) {
  const float* x      = (const float*)d_in[0];
  const float* states = (const float*)d_in[1];
  const float* masks  = (const float*)d_in[2];
  const int*   action = (const int*)d_in[3];
  const float* c1w = (const float*)d_in[4];
  const float* c1b = (const float*)d_in[5];
  const float* c2w = (const float*)d_in[6];
  const float* c2b = (const float*)d_in[7];
  const float* c3w = (const float*)d_in[8];
  const float* c3b = (const float*)d_in[9];
  const float* fcw = (const float*)d_in[10];
  const float* fcb = (const float*)d_in[11];
  const float* wih = (const float*)d_in[12];
  const float* whh = (const float*)d_in[13];
  const float* bih = (const float*)d_in[14];
  const float* bhh = (const float*)d_in[15];
  const float* aw  = (const float*)d_in[16];
  const float* ab  = (const float*)d_in[17];
  const float* cw  = (const float*)d_in[18];
  const float* cb  = (const float*)d_in[19];
  (void)in_sizes; (void)n_in; (void)out_size; (void)ws_size;

  float* ws = (float*)d_ws;
  unsigned short* o1b = (unsigned short*)ws;     // conv1 out bf16
  float* o2    = ws + 14745600;                  // conv2 out fp32
  unsigned short* o3b = (unsigned short*)ws;     // conv3 out bf16 (reuses o1b region after conv2)
  float* xs    = ws + 2359296;
  float* gibuf = ws + 2621440;
  float* outs  = ws + 3407872;
  unsigned int* hbuf = (unsigned int*)(ws + 3670016);   // 2 x 4096 u32 (bf16-packed h slices)
  int*   flags = (int*)(ws + 3686400);
  float* out   = (float*)d_out;

  conv1_mfma<<<1024, 256, 0, stream>>>(x, c1w, c1b, o1b);
  conv2_mfma<<<1568, 256, 0, stream>>>(o1b, c2w, c2b, o2);
  conv3_k<<<dim3(144, 2), 256, 0, stream>>>(o2, c3w, c3b, o3b);
  fc_mfma<<<dim3(8, 8), 256, 0, stream>>>(o3b, fcw, fcb, xs);
  gemm_k<false><<<dim3(48, 16), 256, 0, stream>>>(xs, wih, bih, gibuf, 512, 1536, 512);
  hipMemsetAsync(flags, 0, 1024 * sizeof(int), stream);
  gru_k<<<GRU_NB, 512, 0, stream>>>(gibuf, states, masks, whh, bhh, outs, hbuf, flags, out + 1536);
  heads_k<<<128, 256, 0, stream>>>(outs, action, aw, ab, cw, cb, out);
}